// Round 2
// baseline (2000.456 us; speedup 1.0000x reference)
//
#include <hip/hip_runtime.h>
#include <cstddef>
#include <cstdint>

// AdaConvBlock on MI355X — round 2: f32 baseline, workspace slimmed to ~236MB.
// Never materializes the (B,2304,L) ada temp: each consumer fuses its slice of
// the ada GEMM (K=128 over ST=silu(t_cond)) into its epilogue.
// Pipeline:
//   k_kw (boundary weights) ; k_silu (ST) ; k_mv(x) ;
//   k_modgemm(sh=0,sc=384, src=x)   -> A = y_mod
//   k_scan(A)                       -> A = P (prefix sums)
//   k_conv(A in place)              -> A = y2 (conv + D*y_mod)
//   k_gategemm(gbase=768)           -> out = x + gate_tm*y2
//   k_mv(out) ; k_modgemm(sh=1152,sc=1536, src=out) -> A = y3
//   k_mlp1(w1)                      -> H = gelu(w1@y3 + b1)
//   k_final(w2, gbase=1920)         -> out = out + gate_cm*(w2@H + b2)

namespace {

constexpr int B_  = 16;
constexpr int C_  = 384;
constexpr int L_  = 4096;
constexpr int KADA = 128;       // C/3
constexpr int KS  = 32;
constexpr int NB  = 6 * 33;     // 198 boundary weights per channel
constexpr float EPS_ = 1e-5f;

__device__ __forceinline__ float4 ld4(const float* p) { return *reinterpret_cast<const float4*>(p); }
__device__ __forceinline__ void st4(float* p, float4 v) { *reinterpret_cast<float4*>(p) = v; }
__device__ __forceinline__ float siluf(float z) { return z / (1.f + expf(-z)); }
__device__ __forceinline__ float geluf(float z) { return 0.5f * z * (1.f + erff(z * 0.70710678118654752f)); }

// ---------------- boundary-weight precompute (per channel) ----------------
__global__ __launch_bounds__(64) void k_kw(const float* __restrict__ kern, float* __restrict__ wb) {
  const int c = blockIdx.x;
  const int t = threadIdx.x;
  constexpr float SC[6] = {32.f, 16.f, 8.f, 4.f, 2.f, 1.f};
  constexpr int REP[6] = {1, 1, 2, 4, 8, 16};
  float part = 0.f;
  for (int idx = t; idx < 192; idx += 64) {
    const int i = idx >> 5, r = idx & 31;
    const float v = kern[(i * C_ + c) * KS + r] * SC[i];
    part += v * v * (float)REP[i];
  }
  for (int m = 1; m < 64; m <<= 1) part += __shfl_xor(part, m);
  const float rinv = 1.f / sqrtf(part);
  for (int jj = t; jj < NB; jj += 64) {
    const int i = jj / 33, r = jj - 33 * i;
    const float sc = SC[i] * rinv;
    float bwv;
    if (r == 0) bwv = kern[(i * C_ + c) * KS + 0] * sc;
    else if (r == 32) bwv = -kern[(i * C_ + c) * KS + 31] * sc;
    else bwv = (kern[(i * C_ + c) * KS + r] - kern[(i * C_ + c) * KS + r - 1]) * sc;
    wb[c * NB + jj] = bwv;
  }
}

// ---------------- ST = silu(t_cond), float4 elementwise ----------------
__global__ __launch_bounds__(256) void k_silu(const float* __restrict__ src, float* __restrict__ dst) {
  const size_t n = ((size_t)blockIdx.x * 256 + threadIdx.x) * 4;
  float4 v = ld4(src + n);
  v.x = siluf(v.x); v.y = siluf(v.y); v.z = siluf(v.z); v.w = siluf(v.w);
  st4(dst + n, v);
}

// ---------------- per-(b,l) mean / rsigma over C ----------------
__global__ __launch_bounds__(256) void k_mv(const float* __restrict__ x,
                                            float* __restrict__ mu, float* __restrict__ rs) {
  const int g = blockIdx.x * 256 + threadIdx.x;   // [0, B*L)
  const int b = g >> 12;
  const int l = g & (L_ - 1);
  const float* p = x + (size_t)b * C_ * L_ + l;
  float s = 0.f, ss = 0.f;
  #pragma unroll 4
  for (int c = 0; c < C_; ++c) {
    const float v = p[(size_t)c * L_];
    s += v; ss += v * v;
  }
  const float m = s * (1.f / (float)C_);
  const float var = ss * (1.f / (float)C_) - m * m;
  mu[g] = m;
  rs[g] = 1.f / sqrtf(var + EPS_);
}

// ---------------- fused ada GEMM (shift+scale rows) + LN modulate ----------------
// dst[b,c,l] = (src[b,c,l]-mu)*rs*(1+scale[b,c,l]) + shift[b,c,l]
// shift = ada_w[sh_base+c,:]@ST[b,:,l]+ada_b[sh_base+c]; scale likewise at sc_base.
__global__ __launch_bounds__(256) void k_modgemm(const float* __restrict__ ada_w,
                                                 const float* __restrict__ ada_b,
                                                 const float* __restrict__ ST,
                                                 const float* __restrict__ src,
                                                 const float* __restrict__ mu,
                                                 const float* __restrict__ rs,
                                                 float* __restrict__ dst,
                                                 int sh_base, int sc_base) {
  __shared__ float As1[16][64];
  __shared__ float As2[16][64];
  __shared__ float Bs[16][64];
  const int tid = threadIdx.x;
  const int bb = blockIdx.z;
  const int om = blockIdx.y * 64;
  const int ln = blockIdx.x * 64;
  const int tx = tid & 15, ty = tid >> 4;
  const int ao = tid & 63, ak = tid >> 6;
  const int bl = (tid & 15) * 4, bk = tid >> 4;
  const float* Bp = ST + (size_t)bb * KADA * L_;
  float acc1[4][4] = {}, acc2[4][4] = {};
  for (int k0 = 0; k0 < KADA; k0 += 16) {
    const float4 a1 = ld4(ada_w + (size_t)(sh_base + om + ao) * KADA + k0 + ak * 4);
    const float4 a2 = ld4(ada_w + (size_t)(sc_base + om + ao) * KADA + k0 + ak * 4);
    const float4 b4 = ld4(Bp + (size_t)(k0 + bk) * L_ + ln + bl);
    __syncthreads();
    As1[ak * 4 + 0][ao] = a1.x; As1[ak * 4 + 1][ao] = a1.y;
    As1[ak * 4 + 2][ao] = a1.z; As1[ak * 4 + 3][ao] = a1.w;
    As2[ak * 4 + 0][ao] = a2.x; As2[ak * 4 + 1][ao] = a2.y;
    As2[ak * 4 + 2][ao] = a2.z; As2[ak * 4 + 3][ao] = a2.w;
    Bs[bk][bl + 0] = b4.x; Bs[bk][bl + 1] = b4.y;
    Bs[bk][bl + 2] = b4.z; Bs[bk][bl + 3] = b4.w;
    __syncthreads();
    #pragma unroll
    for (int kk = 0; kk < 16; ++kk) {
      float av1[4], av2[4], bv[4];
      #pragma unroll
      for (int i = 0; i < 4; ++i) { av1[i] = As1[kk][ty * 4 + i]; av2[i] = As2[kk][ty * 4 + i]; }
      #pragma unroll
      for (int j = 0; j < 4; ++j) bv[j] = Bs[kk][tx * 4 + j];
      #pragma unroll
      for (int i = 0; i < 4; ++i)
        #pragma unroll
        for (int j = 0; j < 4; ++j) { acc1[i][j] += av1[i] * bv[j]; acc2[i][j] += av2[i] * bv[j]; }
    }
  }
  const int col = ln + tx * 4;
  const float4 m4 = ld4(mu + (size_t)bb * L_ + col);
  const float4 r4 = ld4(rs + (size_t)bb * L_ + col);
  #pragma unroll
  for (int i = 0; i < 4; ++i) {
    const int r = om + ty * 4 + i;
    const float bsh = ada_b[sh_base + r];
    const float bsc = ada_b[sc_base + r];
    const size_t n = ((size_t)bb * C_ + r) * L_ + col;
    const float4 xv = ld4(src + n);
    float4 o;
    o.x = (xv.x - m4.x) * r4.x * (1.f + acc2[i][0] + bsc) + acc1[i][0] + bsh;
    o.y = (xv.y - m4.y) * r4.y * (1.f + acc2[i][1] + bsc) + acc1[i][1] + bsh;
    o.z = (xv.z - m4.z) * r4.z * (1.f + acc2[i][2] + bsc) + acc1[i][2] + bsh;
    o.w = (xv.w - m4.w) * r4.w * (1.f + acc2[i][3] + bsc) + acc1[i][3] + bsh;
    st4(dst + n, o);
  }
}

// ---------------- in-place inclusive prefix sum along L per (b,c) row ----------------
__device__ __forceinline__ int sidx(int i) { return i + (i >> 4); }

__global__ __launch_bounds__(256) void k_scan(float* __restrict__ data) {
  __shared__ float s[4352];
  __shared__ float aux[256];
  const int tid = threadIdx.x;
  float* row = data + (size_t)blockIdx.x * L_;
  #pragma unroll
  for (int j = 0; j < 16; ++j) s[sidx(j * 256 + tid)] = row[j * 256 + tid];
  __syncthreads();
  const int base = tid * 16;
  float run = 0.f, loc[16];
  #pragma unroll
  for (int j = 0; j < 16; ++j) { run += s[sidx(base + j)]; loc[j] = run; }
  aux[tid] = run;
  __syncthreads();
  for (int off = 1; off < 256; off <<= 1) {
    const float t = (tid >= off) ? aux[tid - off] : 0.f;
    __syncthreads();
    aux[tid] += t;
    __syncthreads();
  }
  const float excl = tid ? aux[tid - 1] : 0.f;
  #pragma unroll
  for (int j = 0; j < 16; ++j) s[sidx(base + j)] = loc[j] + excl;
  __syncthreads();
  #pragma unroll
  for (int j = 0; j < 16; ++j) row[j * 256 + tid] = s[sidx(j * 256 + tid)];
}

// ---------------- conv via boundary weights; in-place A: P -> y2 ----------------
__global__ __launch_bounds__(256) void k_conv(float* __restrict__ A,
                                              const float* __restrict__ wb,
                                              const float* __restrict__ Dv) {
  constexpr int SSTART[6] = {0, 32, 64, 128, 256, 512};
  constexpr int SREP[6]   = {1, 1, 2, 4, 8, 16};
  __shared__ float Q[5120];   // Q[i] = P[i-512] with clamp: 0 below, P[L-1] above
  __shared__ float wl[NB];
  const int tid = threadIdx.x;
  const int c = blockIdx.x % C_;
  float* row = A + (size_t)blockIdx.x * L_;
  Q[tid] = 0.f;
  Q[256 + tid] = 0.f;
  #pragma unroll
  for (int j = 0; j < 16; ++j) Q[512 + j * 256 + tid] = row[j * 256 + tid];
  if (tid < NB) wl[tid] = wb[c * NB + tid];
  __syncthreads();
  const float last = Q[512 + L_ - 1];
  Q[512 + L_ + tid] = last;
  Q[512 + L_ + 256 + tid] = last;
  __syncthreads();

  const float Dc = Dv[c];
  for (int itc = 0; itc < 4; ++itc) {
    float a4[4] = {0.f, 0.f, 0.f, 0.f};
    #pragma unroll
    for (int seg = 0; seg < 6; ++seg) {
      float w[33];
      #pragma unroll
      for (int r = 0; r < 33; ++r) w[r] = wl[seg * 33 + r];
      #pragma unroll
      for (int i4 = 0; i4 < 4; ++i4) {
        const int p = 1024 + tid + (itc * 4 + i4) * 256;  // LDS index of P[l+512]
        float sacc = 0.f;
        #pragma unroll
        for (int r = 0; r < 33; ++r)
          sacc += w[r] * Q[p - (SSTART[seg] + r * SREP[seg])];
        a4[i4] += sacc;
      }
    }
    #pragma unroll
    for (int i4 = 0; i4 < 4; ++i4) {
      const int l = tid + (itc * 4 + i4) * 256;
      const float ymod = Q[512 + l] - Q[511 + l];
      row[l] = a4[i4] + ymod * Dc;   // y2
    }
  }
}

// ---------------- fused gate_tm GEMM + gated residual: out = x + gate*y2 ----------------
__global__ __launch_bounds__(256) void k_gategemm(const float* __restrict__ ada_w,
                                                  const float* __restrict__ ada_b,
                                                  const float* __restrict__ ST,
                                                  const float* __restrict__ x,
                                                  const float* __restrict__ y2,
                                                  float* __restrict__ out,
                                                  int gbase) {
  __shared__ float As[16][64];
  __shared__ float Bs[16][64];
  const int tid = threadIdx.x;
  const int bb = blockIdx.z;
  const int om = blockIdx.y * 64;
  const int ln = blockIdx.x * 64;
  const int tx = tid & 15, ty = tid >> 4;
  const int ao = tid & 63, ak = tid >> 6;
  const int bl = (tid & 15) * 4, bk = tid >> 4;
  const float* Bp = ST + (size_t)bb * KADA * L_;
  float acc[4][4] = {};
  for (int k0 = 0; k0 < KADA; k0 += 16) {
    const float4 a4 = ld4(ada_w + (size_t)(gbase + om + ao) * KADA + k0 + ak * 4);
    const float4 b4 = ld4(Bp + (size_t)(k0 + bk) * L_ + ln + bl);
    __syncthreads();
    As[ak * 4 + 0][ao] = a4.x; As[ak * 4 + 1][ao] = a4.y;
    As[ak * 4 + 2][ao] = a4.z; As[ak * 4 + 3][ao] = a4.w;
    Bs[bk][bl + 0] = b4.x; Bs[bk][bl + 1] = b4.y;
    Bs[bk][bl + 2] = b4.z; Bs[bk][bl + 3] = b4.w;
    __syncthreads();
    #pragma unroll
    for (int kk = 0; kk < 16; ++kk) {
      float av[4], bv[4];
      #pragma unroll
      for (int i = 0; i < 4; ++i) av[i] = As[kk][ty * 4 + i];
      #pragma unroll
      for (int j = 0; j < 4; ++j) bv[j] = Bs[kk][tx * 4 + j];
      #pragma unroll
      for (int i = 0; i < 4; ++i)
        #pragma unroll
        for (int j = 0; j < 4; ++j) acc[i][j] += av[i] * bv[j];
    }
  }
  const int col = ln + tx * 4;
  #pragma unroll
  for (int i = 0; i < 4; ++i) {
    const int r = om + ty * 4 + i;
    const float bg = ada_b[gbase + r];
    const size_t n = ((size_t)bb * C_ + r) * L_ + col;
    const float4 xv = ld4(x + n);
    const float4 yv = ld4(y2 + n);
    float4 o;
    o.x = xv.x + (acc[i][0] + bg) * yv.x;
    o.y = xv.y + (acc[i][1] + bg) * yv.y;
    o.z = xv.z + (acc[i][2] + bg) * yv.z;
    o.w = xv.w + (acc[i][3] + bg) * yv.w;
    st4(out + n, o);
  }
}

// ---------------- MLP GEMM1: H = gelu(w1 @ y3 + b1), K = 384 ----------------
__global__ __launch_bounds__(256) void k_mlp1(const float* __restrict__ w1,
                                              const float* __restrict__ b1,
                                              const float* __restrict__ y3,
                                              float* __restrict__ H) {
  __shared__ float As[16][64];
  __shared__ float Bs[16][64];
  const int tid = threadIdx.x;
  const int bb = blockIdx.z;
  const int om = blockIdx.y * 64;
  const int ln = blockIdx.x * 64;
  const int tx = tid & 15, ty = tid >> 4;
  const int ao = tid & 63, ak = tid >> 6;
  const int bl = (tid & 15) * 4, bk = tid >> 4;
  const float* Bp = y3 + (size_t)bb * C_ * L_;
  float acc[4][4] = {};
  for (int k0 = 0; k0 < C_; k0 += 16) {
    const float4 a4 = ld4(w1 + (size_t)(om + ao) * C_ + k0 + ak * 4);
    const float4 b4 = ld4(Bp + (size_t)(k0 + bk) * L_ + ln + bl);
    __syncthreads();
    As[ak * 4 + 0][ao] = a4.x; As[ak * 4 + 1][ao] = a4.y;
    As[ak * 4 + 2][ao] = a4.z; As[ak * 4 + 3][ao] = a4.w;
    Bs[bk][bl + 0] = b4.x; Bs[bk][bl + 1] = b4.y;
    Bs[bk][bl + 2] = b4.z; Bs[bk][bl + 3] = b4.w;
    __syncthreads();
    #pragma unroll
    for (int kk = 0; kk < 16; ++kk) {
      float av[4], bv[4];
      #pragma unroll
      for (int i = 0; i < 4; ++i) av[i] = As[kk][ty * 4 + i];
      #pragma unroll
      for (int j = 0; j < 4; ++j) bv[j] = Bs[kk][tx * 4 + j];
      #pragma unroll
      for (int i = 0; i < 4; ++i)
        #pragma unroll
        for (int j = 0; j < 4; ++j) acc[i][j] += av[i] * bv[j];
    }
  }
  const int col = ln + tx * 4;
  #pragma unroll
  for (int i = 0; i < 4; ++i) {
    const int r = om + ty * 4 + i;
    const float bo = b1[r];
    float4 v;
    v.x = geluf(acc[i][0] + bo);
    v.y = geluf(acc[i][1] + bo);
    v.z = geluf(acc[i][2] + bo);
    v.w = geluf(acc[i][3] + bo);
    st4(H + ((size_t)bb * C_ + r) * L_ + col, v);
  }
}

// ------- final: out = x2 + gate_cm * (w2 @ H + b2); two-phase K (384 over H, 128 over ST) -------
__global__ __launch_bounds__(256) void k_final(const float* __restrict__ w2,
                                               const float* __restrict__ b2,
                                               const float* __restrict__ H,
                                               const float* __restrict__ ada_w,
                                               const float* __restrict__ ada_b,
                                               const float* __restrict__ ST,
                                               float* __restrict__ out,
                                               int gbase) {
  __shared__ float As[16][64];
  __shared__ float Bs[16][64];
  const int tid = threadIdx.x;
  const int bb = blockIdx.z;
  const int om = blockIdx.y * 64;
  const int ln = blockIdx.x * 64;
  const int tx = tid & 15, ty = tid >> 4;
  const int ao = tid & 63, ak = tid >> 6;
  const int bl = (tid & 15) * 4, bk = tid >> 4;
  float accm[4][4] = {}, accg[4][4] = {};
  // phase 1: w2 @ H, K = 384
  {
    const float* Bp = H + (size_t)bb * C_ * L_;
    for (int k0 = 0; k0 < C_; k0 += 16) {
      const float4 a4 = ld4(w2 + (size_t)(om + ao) * C_ + k0 + ak * 4);
      const float4 b4 = ld4(Bp + (size_t)(k0 + bk) * L_ + ln + bl);
      __syncthreads();
      As[ak * 4 + 0][ao] = a4.x; As[ak * 4 + 1][ao] = a4.y;
      As[ak * 4 + 2][ao] = a4.z; As[ak * 4 + 3][ao] = a4.w;
      Bs[bk][bl + 0] = b4.x; Bs[bk][bl + 1] = b4.y;
      Bs[bk][bl + 2] = b4.z; Bs[bk][bl + 3] = b4.w;
      __syncthreads();
      #pragma unroll
      for (int kk = 0; kk < 16; ++kk) {
        float av[4], bv[4];
        #pragma unroll
        for (int i = 0; i < 4; ++i) av[i] = As[kk][ty * 4 + i];
        #pragma unroll
        for (int j = 0; j < 4; ++j) bv[j] = Bs[kk][tx * 4 + j];
        #pragma unroll
        for (int i = 0; i < 4; ++i)
          #pragma unroll
          for (int j = 0; j < 4; ++j) accm[i][j] += av[i] * bv[j];
      }
    }
  }
  // phase 2: gate_cm = ada_w[gbase..] @ ST, K = 128
  {
    const float* Bp = ST + (size_t)bb * KADA * L_;
    for (int k0 = 0; k0 < KADA; k0 += 16) {
      const float4 a4 = ld4(ada_w + (size_t)(gbase + om + ao) * KADA + k0 + ak * 4);
      const float4 b4 = ld4(Bp + (size_t)(k0 + bk) * L_ + ln + bl);
      __syncthreads();
      As[ak * 4 + 0][ao] = a4.x; As[ak * 4 + 1][ao] = a4.y;
      As[ak * 4 + 2][ao] = a4.z; As[ak * 4 + 3][ao] = a4.w;
      Bs[bk][bl + 0] = b4.x; Bs[bk][bl + 1] = b4.y;
      Bs[bk][bl + 2] = b4.z; Bs[bk][bl + 3] = b4.w;
      __syncthreads();
      #pragma unroll
      for (int kk = 0; kk < 16; ++kk) {
        float av[4], bv[4];
        #pragma unroll
        for (int i = 0; i < 4; ++i) av[i] = As[kk][ty * 4 + i];
        #pragma unroll
        for (int j = 0; j < 4; ++j) bv[j] = Bs[kk][tx * 4 + j];
        #pragma unroll
        for (int i = 0; i < 4; ++i)
          #pragma unroll
          for (int j = 0; j < 4; ++j) accg[i][j] += av[i] * bv[j];
      }
    }
  }
  const int col = ln + tx * 4;
  #pragma unroll
  for (int i = 0; i < 4; ++i) {
    const int r = om + ty * 4 + i;
    const float bo = b2[r];
    const float bg = ada_b[gbase + r];
    const size_t n = ((size_t)bb * C_ + r) * L_ + col;
    const float4 xv = ld4(out + n);
    float4 o;
    o.x = xv.x + (accg[i][0] + bg) * (accm[i][0] + bo);
    o.y = xv.y + (accg[i][1] + bg) * (accm[i][1] + bo);
    o.z = xv.z + (accg[i][2] + bg) * (accm[i][2] + bo);
    o.w = xv.w + (accg[i][3] + bg) * (accm[i][3] + bo);
    st4(out + n, o);
  }
}

}  // namespace

extern "C" void kernel_launch(void* const* d_in, const int* in_sizes, int n_in,
                              void* d_out, int out_size, void* d_ws, size_t ws_size,
                              hipStream_t stream) {
  const float* x      = (const float*)d_in[0];
  const float* t_cond = (const float*)d_in[1];
  const float* kern   = (const float*)d_in[2];
  const float* Dv     = (const float*)d_in[3];
  const float* ada_w  = (const float*)d_in[4];
  const float* ada_b  = (const float*)d_in[5];
  const float* w1     = (const float*)d_in[6];
  const float* b1     = (const float*)d_in[7];
  const float* w2     = (const float*)d_in[8];
  const float* b2     = (const float*)d_in[9];
  float* out = (float*)d_out;

  float* wsf = (float*)d_ws;
  float* A  = wsf;                                   // B*C*L f32 = 100.7MB (y_mod -> P -> y2 -> y3)
  float* H  = A + (size_t)B_ * C_ * L_;              // 100.7MB
  float* ST = H + (size_t)B_ * C_ * L_;              // B*128*L = 33.6MB
  float* MV = ST + (size_t)B_ * KADA * L_;           // 4*B*L = 1MB
  float* WB = MV + 4 * (size_t)B_ * L_;              // 384*198 f32 = 0.3MB
  float* mu1 = MV;
  float* rs1 = MV + (size_t)B_ * L_;
  float* mu2 = MV + 2 * (size_t)B_ * L_;
  float* rs2 = MV + 3 * (size_t)B_ * L_;

  (void)in_sizes; (void)n_in; (void)out_size; (void)ws_size;

  const dim3 gemm_grid(L_ / 64, C_ / 64, B_);

  // boundary weights + silu(t_cond)
  k_kw<<<C_, 64, 0, stream>>>(kern, WB);
  k_silu<<<(B_ * KADA * L_ / 4) / 256, 256, 0, stream>>>(t_cond, ST);
  // LN1 stats; fused mod-GEMM -> y_mod
  k_mv<<<(B_ * L_) / 256, 256, 0, stream>>>(x, mu1, rs1);
  k_modgemm<<<gemm_grid, 256, 0, stream>>>(ada_w, ada_b, ST, x, mu1, rs1, A, 0, C_);
  // prefix sums; conv (in-place y2)
  k_scan<<<B_ * C_, 256, 0, stream>>>(A);
  k_conv<<<B_ * C_, 256, 0, stream>>>(A, WB, Dv);
  // gate_tm GEMM + residual -> out = x2
  k_gategemm<<<gemm_grid, 256, 0, stream>>>(ada_w, ada_b, ST, x, A, out, 2 * C_);
  // LN2 stats; fused mod-GEMM -> y3
  k_mv<<<(B_ * L_) / 256, 256, 0, stream>>>(out, mu2, rs2);
  k_modgemm<<<gemm_grid, 256, 0, stream>>>(ada_w, ada_b, ST, out, mu2, rs2, A, 3 * C_, 4 * C_);
  // MLP
  k_mlp1<<<gemm_grid, 256, 0, stream>>>(w1, b1, A, H);
  k_final<<<gemm_grid, 256, 0, stream>>>(w2, b2, H, ada_w, ada_b, ST, out, 5 * C_);
}

// Round 3
// 683.032 us; speedup vs baseline: 2.9288x; 2.9288x over previous
//
#include <hip/hip_runtime.h>
#include <cstddef>
#include <cstdint>

// AdaConvBlock on MI355X — round 3.
// 1) k_conv rewritten: quad-output per thread + ds_read_b128 (LDS-instr bound fix).
// 2) All GEMMs -> bf16 MFMA 16x16x32 in transposed [l][ch] domain:
//    A = activations [l][k] bf16 (STT / Y3T / HT), B = weights [o][k] bf16.
//    Both K-contiguous -> plain b128 staging, no in-GEMM transposes.
// Buffers (ws, ~221MB): A f32 (y_mod->P->y2) | MV | WB | AWB/W1B/W2B bf16 |
//                       STT bf16 | Y3T bf16 | HT bf16.

namespace {

constexpr int B_  = 16;
constexpr int C_  = 384;
constexpr int L_  = 4096;
constexpr int KADA = 128;
constexpr int KS  = 32;
constexpr int NB  = 6 * 33;
constexpr float EPS_ = 1e-5f;
constexpr int RS = 40;          // LDS row stride (bf16 elems) for GEMM tiles

typedef unsigned short u16;
typedef __attribute__((ext_vector_type(8))) short bf16x8;
typedef __attribute__((ext_vector_type(4))) float f32x4;

__device__ __forceinline__ float4 ld4(const float* p) { return *reinterpret_cast<const float4*>(p); }
__device__ __forceinline__ void st4(float* p, float4 v) { *reinterpret_cast<float4*>(p) = v; }
__device__ __forceinline__ float siluf(float z) { return z / (1.f + expf(-z)); }
__device__ __forceinline__ float geluf(float z) { return 0.5f * z * (1.f + erff(z * 0.70710678118654752f)); }
__device__ __forceinline__ u16 f2b(float x) {
  union { float f; uint32_t u; } a; a.f = x;
  const uint32_t u = a.u;
  return (u16)((u + 0x7fffu + ((u >> 16) & 1u)) >> 16);
}
__device__ __forceinline__ bf16x8 ldb8(const u16* p) { return *reinterpret_cast<const bf16x8*>(p); }
__device__ __forceinline__ void stb8(u16* p, bf16x8 v) { *reinterpret_cast<bf16x8*>(p) = v; }

// ---------------- boundary-weight precompute (per channel) ----------------
__global__ __launch_bounds__(64) void k_kw(const float* __restrict__ kern, float* __restrict__ wb) {
  const int c = blockIdx.x;
  const int t = threadIdx.x;
  constexpr float SC[6] = {32.f, 16.f, 8.f, 4.f, 2.f, 1.f};
  constexpr int REP[6] = {1, 1, 2, 4, 8, 16};
  float part = 0.f;
  for (int idx = t; idx < 192; idx += 64) {
    const int i = idx >> 5, r = idx & 31;
    const float v = kern[(i * C_ + c) * KS + r] * SC[i];
    part += v * v * (float)REP[i];
  }
  for (int m = 1; m < 64; m <<= 1) part += __shfl_xor(part, m);
  const float rinv = 1.f / sqrtf(part);
  for (int jj = t; jj < NB; jj += 64) {
    const int i = jj / 33, r = jj - 33 * i;
    const float sc = SC[i] * rinv;
    float bwv;
    if (r == 0) bwv = kern[(i * C_ + c) * KS + 0] * sc;
    else if (r == 32) bwv = -kern[(i * C_ + c) * KS + 31] * sc;
    else bwv = (kern[(i * C_ + c) * KS + r] - kern[(i * C_ + c) * KS + r - 1]) * sc;
    wb[c * NB + jj] = bwv;
  }
}

// ---------------- weight f32 -> bf16 convert ----------------
__global__ __launch_bounds__(256) void k_wcvt(const float* __restrict__ src, u16* __restrict__ dst) {
  const size_t i = ((size_t)blockIdx.x * 256 + threadIdx.x) * 8;
  const float4 a = ld4(src + i);
  const float4 b = ld4(src + i + 4);
  bf16x8 v;
  v[0] = (short)f2b(a.x); v[1] = (short)f2b(a.y); v[2] = (short)f2b(a.z); v[3] = (short)f2b(a.w);
  v[4] = (short)f2b(b.x); v[5] = (short)f2b(b.y); v[6] = (short)f2b(b.z); v[7] = (short)f2b(b.w);
  stb8(dst + i, v);
}

// ---------------- STT[b][l][128] = bf16(silu(t_cond[b][k][l])) ----------------
__global__ __launch_bounds__(256) void k_tsilu(const float* __restrict__ in, u16* __restrict__ out) {
  __shared__ float T[64][65];
  const int t = threadIdx.x;
  const int lb = blockIdx.x * 64;
  const int kb = blockIdx.y * 64;
  const int b  = blockIdx.z;
  const float* src = in + ((size_t)b * KADA + kb) * L_ + lb;
  const int ll = t & 63;
  const int kq = t >> 6;                      // 0..3
  #pragma unroll
  for (int j = 0; j < 16; ++j) {
    const int k = kq * 16 + j;
    T[k][ll] = siluf(src[(size_t)k * L_ + ll]);
  }
  __syncthreads();
  const int g = t & 7;                         // k-oct
  #pragma unroll
  for (int j = 0; j < 2; ++j) {
    const int l = (t >> 3) + 32 * j;
    bf16x8 v;
    #pragma unroll
    for (int i = 0; i < 8; ++i) v[i] = (short)f2b(T[8 * g + i][l]);
    stb8(out + ((size_t)b * L_ + lb + l) * KADA + kb + 8 * g, v);
  }
}

// ---------------- per-(b,l) mean / rsigma over C ----------------
__global__ __launch_bounds__(256) void k_mv(const float* __restrict__ x,
                                            float* __restrict__ mu, float* __restrict__ rs) {
  const int g = blockIdx.x * 256 + threadIdx.x;
  const int b = g >> 12;
  const int l = g & (L_ - 1);
  const float* p = x + (size_t)b * C_ * L_ + l;
  float s = 0.f, ss = 0.f;
  #pragma unroll 4
  for (int c = 0; c < C_; ++c) {
    const float v = p[(size_t)c * L_];
    s += v; ss += v * v;
  }
  const float m = s * (1.f / (float)C_);
  const float var = ss * (1.f / (float)C_) - m * m;
  mu[g] = m;
  rs[g] = 1.f / sqrtf(var + EPS_);
}

// ---------------- MFMA GEMM core, transposed domain ----------------
// out[l][c] = sum_k Act[l][k] * W[c][k].  Block tile 128l x 64c, 4 waves
// (wave: 64l x 32c = 4x2 frags of 16x16, K-step 32).
template <int KD, int NBOP>
__device__ __forceinline__ void gemm_core(const u16* __restrict__ Ab,
                                          const u16* __restrict__ B0b,
                                          const u16* __restrict__ B1b,
                                          u16* As, u16* Bs0, u16* Bs1,
                                          f32x4 (&acc0)[4][2], f32x4 (&acc1)[4][2]) {
  const int tid = threadIdx.x;
  const int g = tid & 3;
  const int ar = tid >> 2;                 // 0..63
  const int lane = tid & 63;
  const int wid = tid >> 6;
  const int l0w = (wid & 1) * 64;
  const int c0w = (wid >> 1) * 32;
  const int frow = lane & 15;
  const int fk = (lane >> 4) * 8;
  for (int k0 = 0; k0 < KD; k0 += 32) {
    const bf16x8 a0 = ldb8(Ab + (size_t)ar * KD + k0 + 8 * g);
    const bf16x8 a1 = ldb8(Ab + (size_t)(64 + ar) * KD + k0 + 8 * g);
    const bf16x8 b0 = ldb8(B0b + (size_t)ar * KD + k0 + 8 * g);
    bf16x8 b1{};
    if constexpr (NBOP == 2) b1 = ldb8(B1b + (size_t)ar * KD + k0 + 8 * g);
    __syncthreads();
    stb8(As + ar * RS + 8 * g, a0);
    stb8(As + (64 + ar) * RS + 8 * g, a1);
    stb8(Bs0 + ar * RS + 8 * g, b0);
    if constexpr (NBOP == 2) stb8(Bs1 + ar * RS + 8 * g, b1);
    __syncthreads();
    bf16x8 af[4], bf0[2], bf1[2];
    #pragma unroll
    for (int fi = 0; fi < 4; ++fi)
      af[fi] = ldb8(As + (l0w + fi * 16 + frow) * RS + fk);
    #pragma unroll
    for (int fj = 0; fj < 2; ++fj) {
      bf0[fj] = ldb8(Bs0 + (c0w + fj * 16 + frow) * RS + fk);
      if constexpr (NBOP == 2) bf1[fj] = ldb8(Bs1 + (c0w + fj * 16 + frow) * RS + fk);
    }
    #pragma unroll
    for (int fi = 0; fi < 4; ++fi)
      #pragma unroll
      for (int fj = 0; fj < 2; ++fj) {
        acc0[fi][fj] = __builtin_amdgcn_mfma_f32_16x16x32_bf16(af[fi], bf0[fj], acc0[fi][fj], 0, 0, 0);
        if constexpr (NBOP == 2)
          acc1[fi][fj] = __builtin_amdgcn_mfma_f32_16x16x32_bf16(af[fi], bf1[fj], acc1[fi][fj], 0, 0, 0);
      }
  }
}

// ---------------- ada GEMMs: MODE 0 = LN1-mod -> y_mod f32 [c][l]
//                  MODE 1 = LN2-mod -> Y3T bf16 [l][c]
//                  MODE 2 = gate_tm -> out = x + g*y2 (f32 [c][l]) ----------------
template <int MODE>
__global__ __launch_bounds__(256) void k_adagemm(const u16* __restrict__ AWB,
                                                 const float* __restrict__ ada_b,
                                                 const u16* __restrict__ STT,
                                                 const float* __restrict__ src,
                                                 const float* __restrict__ aux,
                                                 const float* __restrict__ mu,
                                                 const float* __restrict__ rs,
                                                 float* __restrict__ dstf,
                                                 u16* __restrict__ dstb,
                                                 int base0, int base1) {
  __shared__ u16 As[128 * RS];
  __shared__ u16 Bs0[64 * RS];
  __shared__ u16 Bs1[64 * RS];
  const int lb = blockIdx.x * 128;
  const int cb = blockIdx.y * 64;
  const int b  = blockIdx.z;
  f32x4 acc0[4][2] = {};
  f32x4 acc1[4][2] = {};
  constexpr int NBOP = (MODE == 2) ? 1 : 2;
  gemm_core<KADA, NBOP>(STT + ((size_t)b * L_ + lb) * KADA,
                        AWB + (size_t)(base0 + cb) * KADA,
                        AWB + (size_t)(base1 + cb) * KADA,
                        As, Bs0, Bs1, acc0, acc1);
  const int lane = threadIdx.x & 63;
  const int wid = threadIdx.x >> 6;
  const int l0w = (wid & 1) * 64;
  const int c0w = (wid >> 1) * 32;
  const int frow = lane & 15;
  const int fq = (lane >> 4) * 4;
  #pragma unroll
  for (int fi = 0; fi < 4; ++fi) {
    const int lg = lb + l0w + fi * 16 + fq;
    float4 m4, r4;
    if (MODE != 2) { m4 = ld4(mu + (size_t)b * L_ + lg); r4 = ld4(rs + (size_t)b * L_ + lg); }
    #pragma unroll
    for (int fj = 0; fj < 2; ++fj) {
      const int cg = cb + c0w + fj * 16 + frow;
      const size_t n = ((size_t)b * C_ + cg) * L_ + lg;
      if (MODE == 2) {
        const float bg = ada_b[base0 + cg];
        const float4 xv = ld4(src + n);
        const float4 yv = ld4(aux + n);
        float4 o;
        o.x = xv.x + (acc0[fi][fj][0] + bg) * yv.x;
        o.y = xv.y + (acc0[fi][fj][1] + bg) * yv.y;
        o.z = xv.z + (acc0[fi][fj][2] + bg) * yv.z;
        o.w = xv.w + (acc0[fi][fj][3] + bg) * yv.w;
        st4(dstf + n, o);
      } else {
        const float bsh = ada_b[base0 + cg];
        const float bsc = ada_b[base1 + cg];
        const float4 xv = ld4(src + n);
        float o[4];
        o[0] = (xv.x - m4.x) * r4.x * (1.f + acc1[fi][fj][0] + bsc) + acc0[fi][fj][0] + bsh;
        o[1] = (xv.y - m4.y) * r4.y * (1.f + acc1[fi][fj][1] + bsc) + acc0[fi][fj][1] + bsh;
        o[2] = (xv.z - m4.z) * r4.z * (1.f + acc1[fi][fj][2] + bsc) + acc0[fi][fj][2] + bsh;
        o[3] = (xv.w - m4.w) * r4.w * (1.f + acc1[fi][fj][3] + bsc) + acc0[fi][fj][3] + bsh;
        if (MODE == 0) {
          st4(dstf + n, float4{o[0], o[1], o[2], o[3]});
        } else {
          u16* d = dstb + ((size_t)b * L_ + lg) * C_ + cg;
          #pragma unroll
          for (int i = 0; i < 4; ++i) d[(size_t)i * C_] = f2b(o[i]);
        }
      }
    }
  }
}

// ---------------- MLP GEMM1: HT[l][h] = bf16(gelu(sum_c Y3T[l][c]*W1[h][c] + b1)) ----------------
__global__ __launch_bounds__(256) void k_mlp1(const u16* __restrict__ Y3T,
                                              const u16* __restrict__ W1B,
                                              const float* __restrict__ b1,
                                              u16* __restrict__ HT) {
  __shared__ u16 As[128 * RS];
  __shared__ u16 Bs0[64 * RS];
  const int lb = blockIdx.x * 128;
  const int cb = blockIdx.y * 64;
  const int b  = blockIdx.z;
  f32x4 acc0[4][2] = {};
  f32x4 accd[4][2];
  gemm_core<C_, 1>(Y3T + ((size_t)b * L_ + lb) * C_, W1B + (size_t)cb * C_, nullptr,
                   As, Bs0, Bs0, acc0, accd);
  const int lane = threadIdx.x & 63;
  const int wid = threadIdx.x >> 6;
  const int l0w = (wid & 1) * 64;
  const int c0w = (wid >> 1) * 32;
  const int frow = lane & 15;
  const int fq = (lane >> 4) * 4;
  #pragma unroll
  for (int fi = 0; fi < 4; ++fi) {
    const int lg = lb + l0w + fi * 16 + fq;
    #pragma unroll
    for (int fj = 0; fj < 2; ++fj) {
      const int hg = cb + c0w + fj * 16 + frow;
      const float bo = b1[hg];
      u16* d = HT + ((size_t)b * L_ + lg) * C_ + hg;
      #pragma unroll
      for (int i = 0; i < 4; ++i) d[(size_t)i * C_] = f2b(geluf(acc0[fi][fj][i] + bo));
    }
  }
}

// ---------------- final: out = x2 + gate_cm * (w2@H + b2) ----------------
__global__ __launch_bounds__(256) void k_final(const u16* __restrict__ HT,
                                               const u16* __restrict__ W2B,
                                               const float* __restrict__ b2,
                                               const u16* __restrict__ AWB,
                                               const float* __restrict__ ada_b,
                                               const u16* __restrict__ STT,
                                               float* __restrict__ out,
                                               int gbase) {
  __shared__ u16 As[128 * RS];
  __shared__ u16 Bs0[64 * RS];
  const int lb = blockIdx.x * 128;
  const int cb = blockIdx.y * 64;
  const int b  = blockIdx.z;
  f32x4 accM[4][2] = {};
  f32x4 accG[4][2] = {};
  f32x4 accd[4][2];
  gemm_core<C_, 1>(HT + ((size_t)b * L_ + lb) * C_, W2B + (size_t)cb * C_, nullptr,
                   As, Bs0, Bs0, accM, accd);
  gemm_core<KADA, 1>(STT + ((size_t)b * L_ + lb) * KADA,
                     AWB + (size_t)(gbase + cb) * KADA, nullptr,
                     As, Bs0, Bs0, accG, accd);
  const int lane = threadIdx.x & 63;
  const int wid = threadIdx.x >> 6;
  const int l0w = (wid & 1) * 64;
  const int c0w = (wid >> 1) * 32;
  const int frow = lane & 15;
  const int fq = (lane >> 4) * 4;
  #pragma unroll
  for (int fi = 0; fi < 4; ++fi) {
    const int lg = lb + l0w + fi * 16 + fq;
    #pragma unroll
    for (int fj = 0; fj < 2; ++fj) {
      const int cg = cb + c0w + fj * 16 + frow;
      const float bo = b2[cg];
      const float bg = ada_b[gbase + cg];
      const size_t n = ((size_t)b * C_ + cg) * L_ + lg;
      const float4 xv = ld4(out + n);
      float4 o;
      o.x = xv.x + (accG[fi][fj][0] + bg) * (accM[fi][fj][0] + bo);
      o.y = xv.y + (accG[fi][fj][1] + bg) * (accM[fi][fj][1] + bo);
      o.z = xv.z + (accG[fi][fj][2] + bg) * (accM[fi][fj][2] + bo);
      o.w = xv.w + (accG[fi][fj][3] + bg) * (accM[fi][fj][3] + bo);
      st4(out + n, o);
    }
  }
}

// ---------------- in-place inclusive prefix sum along L per (b,c) row ----------------
__device__ __forceinline__ int sidx(int i) { return i + (i >> 4); }

__global__ __launch_bounds__(256) void k_scan(float* __restrict__ data) {
  __shared__ float s[4352];
  __shared__ float aux[256];
  const int tid = threadIdx.x;
  float* row = data + (size_t)blockIdx.x * L_;
  #pragma unroll
  for (int j = 0; j < 16; ++j) s[sidx(j * 256 + tid)] = row[j * 256 + tid];
  __syncthreads();
  const int base = tid * 16;
  float run = 0.f, loc[16];
  #pragma unroll
  for (int j = 0; j < 16; ++j) { run += s[sidx(base + j)]; loc[j] = run; }
  aux[tid] = run;
  __syncthreads();
  for (int off = 1; off < 256; off <<= 1) {
    const float t = (tid >= off) ? aux[tid - off] : 0.f;
    __syncthreads();
    aux[tid] += t;
    __syncthreads();
  }
  const float excl = tid ? aux[tid - 1] : 0.f;
  #pragma unroll
  for (int j = 0; j < 16; ++j) s[sidx(base + j)] = loc[j] + excl;
  __syncthreads();
  #pragma unroll
  for (int j = 0; j < 16; ++j) row[j * 256 + tid] = s[sidx(j * 256 + tid)];
}

// ---------------- conv via boundary weights; quad outputs + b128 reads ----------------
__global__ __launch_bounds__(256) void k_conv(float* __restrict__ A,
                                              const float* __restrict__ wb,
                                              const float* __restrict__ Dv) {
  __shared__ float Q[5120];     // Q[i] = P[i-512]; 0 below, P[L-1] above
  __shared__ float wl[NB];
  const int tid = threadIdx.x;
  const int c = blockIdx.x % C_;
  float* row = A + (size_t)blockIdx.x * L_;
  float4* Q4 = reinterpret_cast<float4*>(Q);
  if (tid < 128) Q4[tid] = float4{0.f, 0.f, 0.f, 0.f};
  #pragma unroll
  for (int j = 0; j < 4; ++j)
    Q4[128 + j * 256 + tid] = ld4(row + (size_t)(j * 256 + tid) * 4);
  if (tid < NB) wl[tid] = wb[c * NB + tid];
  __syncthreads();
  const float last = Q[512 + L_ - 1];
  if (tid < 128) Q4[1152 + tid] = float4{last, last, last, last};
  __syncthreads();

  const float Dc = Dv[c];
  float acc[4][4];
  #pragma unroll
  for (int q = 0; q < 4; ++q)
    #pragma unroll
    for (int i = 0; i < 4; ++i) acc[q][i] = 0.f;

  constexpr int SS[6] = {0, 32, 64, 128, 256, 512};
  #pragma unroll
  for (int seg = 0; seg < 6; ++seg) {
    float w[33];
    #pragma unroll
    for (int r = 0; r < 33; ++r) w[r] = wl[seg * 33 + r];
    #pragma unroll
    for (int q = 0; q < 4; ++q) {
      const int p4 = 256 + q * 256 + tid;      // (p0)/4, p0 = 1024 + 4*(q*256+tid)
      if (seg < 2) {
        float4 win[9];
        const int base = p4 - (SS[seg] >> 2) - 8;
        #pragma unroll
        for (int j = 0; j < 9; ++j) win[j] = Q4[base + j];
        const float* wf = reinterpret_cast<const float*>(win);
        #pragma unroll
        for (int i = 0; i < 4; ++i) {
          float s = 0.f;
          #pragma unroll
          for (int r = 0; r < 33; ++r) s += w[r] * wf[32 + i - r];
          acc[q][i] += s;
        }
      } else if (seg == 2) {
        float4 win[17];
        #pragma unroll
        for (int j = 0; j < 17; ++j) win[j] = Q4[p4 - 32 + j];
        const float* wf = reinterpret_cast<const float*>(win);
        #pragma unroll
        for (int i = 0; i < 4; ++i) {
          float s = 0.f;
          #pragma unroll
          for (int r = 0; r < 33; ++r) s += w[r] * wf[64 + i - 2 * r];
          acc[q][i] += s;
        }
      } else {
        const int step = (seg == 3) ? 1 : (seg == 4) ? 2 : 4;
        const int b0 = p4 - (SS[seg] >> 2);
        float s0 = 0.f, s1 = 0.f, s2 = 0.f, s3 = 0.f;
        #pragma unroll
        for (int r = 0; r < 33; ++r) {
          const float4 v = Q4[b0 - r * step];
          s0 += w[r] * v.x; s1 += w[r] * v.y; s2 += w[r] * v.z; s3 += w[r] * v.w;
        }
        acc[q][0] += s0; acc[q][1] += s1; acc[q][2] += s2; acc[q][3] += s3;
      }
    }
  }
  #pragma unroll
  for (int q = 0; q < 4; ++q) {
    const int l0 = (q * 256 + tid) * 4;
    const float4 cur = Q4[128 + (l0 >> 2)];
    const float pm1 = Q[511 + l0];
    float4 o;
    o.x = acc[q][0] + (cur.x - pm1) * Dc;
    o.y = acc[q][1] + (cur.y - cur.x) * Dc;
    o.z = acc[q][2] + (cur.z - cur.y) * Dc;
    o.w = acc[q][3] + (cur.w - cur.z) * Dc;
    st4(row + l0, o);
  }
}

}  // namespace

extern "C" void kernel_launch(void* const* d_in, const int* in_sizes, int n_in,
                              void* d_out, int out_size, void* d_ws, size_t ws_size,
                              hipStream_t stream) {
  const float* x      = (const float*)d_in[0];
  const float* t_cond = (const float*)d_in[1];
  const float* kern   = (const float*)d_in[2];
  const float* Dv     = (const float*)d_in[3];
  const float* ada_w  = (const float*)d_in[4];
  const float* ada_b  = (const float*)d_in[5];
  const float* w1     = (const float*)d_in[6];
  const float* b1     = (const float*)d_in[7];
  const float* w2     = (const float*)d_in[8];
  const float* b2     = (const float*)d_in[9];
  float* out = (float*)d_out;

  float* wsf = (float*)d_ws;
  float* A  = wsf;                                       // 25.17M f32
  float* MV = A + (size_t)B_ * C_ * L_;                  // 262144 f32
  float* WB = MV + 4 * (size_t)B_ * L_;                  // 76032 f32
  u16* AWB = (u16*)(WB + (size_t)C_ * NB);               // 294912 bf16
  u16* W1B = AWB + (size_t)6 * C_ * KADA;                // 147456
  u16* W2B = W1B + (size_t)C_ * C_;                      // 147456
  u16* STT = W2B + (size_t)C_ * C_;                      // 8.39M
  u16* Y3T = STT + (size_t)B_ * L_ * KADA;               // 25.17M
  u16* HT  = Y3T + (size_t)B_ * L_ * C_;                 // 25.17M
  float* mu1 = MV;
  float* rs1 = MV + (size_t)B_ * L_;
  float* mu2 = MV + 2 * (size_t)B_ * L_;
  float* rs2 = MV + 3 * (size_t)B_ * L_;

  (void)in_sizes; (void)n_in; (void)out_size; (void)ws_size;

  const dim3 gg(L_ / 128, C_ / 64, B_);   // (32, 6, 16)

  k_kw<<<C_, 64, 0, stream>>>(kern, WB);
  k_wcvt<<<(6 * C_ * KADA) / 2048, 256, 0, stream>>>(ada_w, AWB);
  k_wcvt<<<(C_ * C_) / 2048, 256, 0, stream>>>(w1, W1B);
  k_wcvt<<<(C_ * C_) / 2048, 256, 0, stream>>>(w2, W2B);
  k_tsilu<<<dim3(L_ / 64, KADA / 64, B_), 256, 0, stream>>>(t_cond, STT);

  k_mv<<<(B_ * L_) / 256, 256, 0, stream>>>(x, mu1, rs1);
  // LN1 modulate -> y_mod (A, f32)
  k_adagemm<0><<<gg, 256, 0, stream>>>(AWB, ada_b, STT, x, nullptr, mu1, rs1, A, nullptr, 0, C_);
  // prefix sums; conv (in-place y2)
  k_scan<<<B_ * C_, 256, 0, stream>>>(A);
  k_conv<<<B_ * C_, 256, 0, stream>>>(A, WB, Dv);
  // gate_tm + residual -> out = x2
  k_adagemm<2><<<gg, 256, 0, stream>>>(AWB, ada_b, STT, x, A, nullptr, nullptr, out, nullptr, 2 * C_, 0);
  // LN2 modulate -> Y3T (bf16, transposed)
  k_mv<<<(B_ * L_) / 256, 256, 0, stream>>>(out, mu2, rs2);
  k_adagemm<1><<<gg, 256, 0, stream>>>(AWB, ada_b, STT, out, nullptr, mu2, rs2, nullptr, Y3T, 3 * C_, 4 * C_);
  // MLP
  k_mlp1<<<gg, 256, 0, stream>>>(Y3T, W1B, b1, HT);
  k_final<<<gg, 256, 0, stream>>>(HT, W2B, b2, AWB, ada_b, STT, out, 5 * C_);
}